// Round 12
// baseline (562.133 us; speedup 1.0000x reference)
//
#include <hip/hip_runtime.h>
#include <hip/hip_bf16.h>

#define B_ 4
#define S_ 2048
#define D_ 1024
#define H_ 16
#define TSZ 8388608L  // B*S*D elements

typedef short short8 __attribute__((ext_vector_type(8)));
typedef float f32x4 __attribute__((ext_vector_type(4)));

__device__ inline unsigned short f2b(float f) {
  __hip_bfloat16 h = __float2bfloat16(f);
  return __builtin_bit_cast(unsigned short, h);
}
// async global->LDS, 16 bytes per lane; LDS dest must be wave-uniform base
__device__ inline void gld16(const unsigned short* g, unsigned short* l) {
  __builtin_amdgcn_global_load_lds(
      (const __attribute__((address_space(1))) void*)g,
      (__attribute__((address_space(3))) void*)l, 16, 0, 0);
}

// ------- fused f32->bf16 convert (Q,K,V) + mask bit-pack (one launch) ------
__global__ __launch_bounds__(256) void cvt3m(
    const float* __restrict__ Q, const float* __restrict__ K,
    const float* __restrict__ V, const int* __restrict__ mask,
    unsigned short* __restrict__ qo, unsigned short* __restrict__ ko,
    unsigned short* __restrict__ vo, unsigned int* __restrict__ mp) {
  if (blockIdx.x < 12288) {
    int seg = blockIdx.x >> 12;
    long i = ((long)(blockIdx.x & 4095) * 256 + threadIdx.x) * 8;
    const float* in = seg == 0 ? Q : seg == 1 ? K : V;
    unsigned short* out = seg == 0 ? qo : seg == 1 ? ko : vo;
    float4 a = *(const float4*)(in + i);
    float4 b = *(const float4*)(in + i + 4);
    short8 u;
    u[0] = (short)f2b(a.x); u[1] = (short)f2b(a.y);
    u[2] = (short)f2b(a.z); u[3] = (short)f2b(a.w);
    u[4] = (short)f2b(b.x); u[5] = (short)f2b(b.y);
    u[6] = (short)f2b(b.z); u[7] = (short)f2b(b.w);
    *(short8*)(out + i) = u;
  } else {
    long t = (long)(blockIdx.x - 12288) * 256 + threadIdx.x;  // row*16 + kt
    const int4* p = (const int4*)(mask + (t >> 4) * (long)S_ + (t & 15) * 128);
    unsigned int w0 = 0, w1 = 0, w2 = 0, w3 = 0;
#pragma unroll
    for (int c = 0; c < 32; c++) {
      int4 v = p[c];
#pragma unroll
      for (int e = 0; e < 4; e++) {
        int k = c * 4 + e;
        int val = e == 0 ? v.x : e == 1 ? v.y : e == 2 ? v.z : v.w;
        int nb = k >> 4, p16 = k & 15;
        int gg = p16 >> 2, r = p16 & 3;
        unsigned bit = ((unsigned)val & 1u) << (nb * 4 + r);
        if (gg == 0) w0 |= bit; else if (gg == 1) w1 |= bit;
        else if (gg == 2) w2 |= bit; else w3 |= bit;
      }
    }
    *(uint4*)(mp + t * 4) = make_uint4(w0, w1, w2, w3);
  }
}

// ---------------- weight transpose x4: W f32 [K][N] -> Wt bf16 [N][K] ------
__global__ __launch_bounds__(256) void transpose_w4(
    const float* __restrict__ W0, const float* __restrict__ W1,
    const float* __restrict__ W2, const float* __restrict__ W3,
    unsigned short* __restrict__ T0, unsigned short* __restrict__ T1,
    unsigned short* __restrict__ T2, unsigned short* __restrict__ T3) {
  __shared__ unsigned short t[64 * 72];  // [k][n] pitch 72
  const int z = blockIdx.z;
  const float* W = z == 0 ? W0 : z == 1 ? W1 : z == 2 ? W2 : W3;
  unsigned short* Wt = z == 0 ? T0 : z == 1 ? T1 : z == 2 ? T2 : T3;
  const int tid = threadIdx.x;
  const int k0 = blockIdx.x * 64, n0 = blockIdx.y * 64;
#pragma unroll
  for (int p = 0; p < 4; p++) {
    int e = (p * 256 + tid) * 4;
    int r = e >> 6, c = e & 63;
    float4 v = *(const float4*)(W + (long)(k0 + r) * D_ + n0 + c);
    ushort4 u;
    u.x = f2b(v.x); u.y = f2b(v.y); u.z = f2b(v.z); u.w = f2b(v.w);
    *(ushort4*)(&t[r * 72 + c]) = u;
  }
  __syncthreads();
#pragma unroll
  for (int p = 0; p < 2; p++) {
    int e = (p * 256 + tid) * 8;
    int n = e >> 6, kc = e & 63;
    short8 x;
#pragma unroll
    for (int i = 0; i < 8; i++) x[i] = (short)t[(kc + i) * 72 + n];
    *(short8*)(Wt + (long)(n0 + n) * D_ + k0 + kc) = x;
  }
}

// ---------------- fused QKV projection GEMM --------------------------------
// z=0: Q->qh (head-major), z=1: K->kh (head-major), z=2: V->vt (b,h,dd,s)
__global__ __launch_bounds__(256) void qkv_gemm(
    const unsigned short* __restrict__ qa, const unsigned short* __restrict__ ka,
    const unsigned short* __restrict__ va, const unsigned short* __restrict__ wq,
    const unsigned short* __restrict__ wk, const unsigned short* __restrict__ wv,
    const float* __restrict__ bqp, const float* __restrict__ bkp,
    const float* __restrict__ bvp, unsigned short* __restrict__ qo,
    unsigned short* __restrict__ ko, unsigned short* __restrict__ vo) {
  __shared__ unsigned short Asm[128 * 32];
  __shared__ unsigned short Bsm[128 * 32];
  const int z = blockIdx.z;
  const unsigned short* A = z == 0 ? qa : z == 1 ? ka : va;
  const unsigned short* Wt = z == 0 ? wq : z == 1 ? wk : wv;
  const float* bias = z == 0 ? bqp : z == 1 ? bkp : bvp;
  unsigned short* outp = z == 0 ? qo : z == 1 ? ko : vo;
  const int tid = threadIdx.x;
  const int lane = tid & 63, wid = tid >> 6;
  const int g = lane >> 4, li = lane & 15;
  const int wm = wid >> 1, wn = wid & 1;
  const long bm = (long)blockIdx.x * 128;
  const long bn = (long)blockIdx.y * 128;

  f32x4 acc[4][4];
#pragma unroll
  for (int i = 0; i < 4; i++)
#pragma unroll
    for (int j = 0; j < 4; j++) acc[i][j] = (f32x4){0.f, 0.f, 0.f, 0.f};

  for (int kt = 0; kt < 32; ++kt) {
    const int k0 = kt * 32;
    __syncthreads();
#pragma unroll
    for (int p = 0; p < 2; p++) {
      int ci = p * 256 + wid * 64 + lane;
      int r = ci >> 2, c = (ci & 3) * 8;
      gld16(A + (bm + r) * 1024L + k0 + c, &Asm[(p * 256 + wid * 64) * 8]);
      gld16(Wt + (bn + r) * 1024L + k0 + c, &Bsm[(p * 256 + wid * 64) * 8]);
    }
    __syncthreads();
    short8 af[4], bf[4];
#pragma unroll
    for (int i = 0; i < 4; i++)
      af[i] = *(const short8*)(&Asm[(wm * 64 + i * 16 + li) * 32 + g * 8]);
#pragma unroll
    for (int i = 0; i < 4; i++)
      bf[i] = *(const short8*)(&Bsm[(wn * 64 + i * 16 + li) * 32 + g * 8]);
#pragma unroll
    for (int i = 0; i < 4; i++)
#pragma unroll
      for (int j = 0; j < 4; j++)
        acc[i][j] =
            __builtin_amdgcn_mfma_f32_16x16x32_bf16(af[i], bf[j], acc[i][j], 0, 0, 0);
  }

#pragma unroll
  for (int i = 0; i < 4; i++) {
    int row0 = (int)bm + wm * 64 + i * 16 + g * 4;
#pragma unroll
    for (int j = 0; j < 4; j++) {
      int col = (int)bn + wn * 64 + j * 16 + li;
      float bvv = bias[col];
      if (z == 2) {
        int b = row0 >> 11, s0 = row0 & 2047;
        int h = col >> 6, dd = col & 63;
        ushort4 u;
#pragma unroll
        for (int jj = 0; jj < 4; jj++) u[jj] = f2b(acc[i][j][jj] + bvv);
        *(ushort4*)(outp + ((long)(b * H_ + h) * 64 + dd) * S_ + s0) = u;
      } else {
#pragma unroll
        for (int jj = 0; jj < 4; jj++) {
          int row = row0 + jj;
          int b = row >> 11, s = row & 2047;
          int h = col >> 6, dd = col & 63;
          outp[(((long)(b * H_ + h)) * S_ + s) * 64 + dd] =
              f2b(acc[i][j][jj] + bvv);
        }
      }
    }
  }
}

// ---------------- output GEMM: out = ctx @ Wo^T + bo (f32 out) -------------
__global__ __launch_bounds__(256) void wo_gemm(
    const unsigned short* __restrict__ A, const unsigned short* __restrict__ Wt,
    const float* __restrict__ bias, float* __restrict__ out) {
  __shared__ unsigned short Asm[128 * 32];
  __shared__ unsigned short Bsm[128 * 32];
  const int tid = threadIdx.x;
  const int lane = tid & 63, wid = tid >> 6;
  const int g = lane >> 4, li = lane & 15;
  const int wm = wid >> 1, wn = wid & 1;
  const long bm = (long)blockIdx.x * 128;
  const long bn = (long)blockIdx.y * 128;

  f32x4 acc[4][4];
#pragma unroll
  for (int i = 0; i < 4; i++)
#pragma unroll
    for (int j = 0; j < 4; j++) acc[i][j] = (f32x4){0.f, 0.f, 0.f, 0.f};

  for (int kt = 0; kt < 32; ++kt) {
    const int k0 = kt * 32;
    __syncthreads();
#pragma unroll
    for (int p = 0; p < 2; p++) {
      int ci = p * 256 + wid * 64 + lane;
      int r = ci >> 2, c = (ci & 3) * 8;
      gld16(A + (bm + r) * 1024L + k0 + c, &Asm[(p * 256 + wid * 64) * 8]);
      gld16(Wt + (bn + r) * 1024L + k0 + c, &Bsm[(p * 256 + wid * 64) * 8]);
    }
    __syncthreads();
    short8 af[4], bf[4];
#pragma unroll
    for (int i = 0; i < 4; i++)
      af[i] = *(const short8*)(&Asm[(wm * 64 + i * 16 + li) * 32 + g * 8]);
#pragma unroll
    for (int i = 0; i < 4; i++)
      bf[i] = *(const short8*)(&Bsm[(wn * 64 + i * 16 + li) * 32 + g * 8]);
#pragma unroll
    for (int i = 0; i < 4; i++)
#pragma unroll
      for (int j = 0; j < 4; j++)
        acc[i][j] =
            __builtin_amdgcn_mfma_f32_16x16x32_bf16(af[i], bf[j], acc[i][j], 0, 0, 0);
  }

#pragma unroll
  for (int i = 0; i < 4; i++) {
    int row0 = (int)bm + wm * 64 + i * 16 + g * 4;
#pragma unroll
    for (int j = 0; j < 4; j++) {
      int col = (int)bn + wn * 64 + j * 16 + li;
      float bvv = bias[col];
#pragma unroll
      for (int jj = 0; jj < 4; jj++)
        out[(long)(row0 + jj) * 1024 + col] = acc[i][j][jj] + bvv;
    }
  }
}

// -------- pass 1: q-wide lsum kernel (256 q-rows/block, 4 sub-tiles/wave) --
__global__ __launch_bounds__(256, 2) void lsum_kernel(
    const unsigned short* __restrict__ q,   // (BH,S,64)
    const unsigned short* __restrict__ k,   // (BH,S,64)
    const unsigned int* __restrict__ mpk,   // packed mask
    float* __restrict__ linvb) {            // (BH,S) 1/lsum
  __shared__ unsigned short k_lds[128 * 72];  // [key][dd] pitch 72
  const int tid = threadIdx.x;
  const int lane = tid & 63, w = tid >> 6;
  const int g = lane >> 4, li = lane & 15;
  // XCD swizzle (bijective over 512 = 8 xcd * 8 bx * 8 head-slots)
  const int p0 = blockIdx.x + 8 * blockIdx.y;
  const int xcd = p0 & 7, q8 = p0 >> 3;
  const int bx = q8 & 7, bh = xcd * 8 + (q8 >> 3);
  const int b = bh >> 4;
  const int qbase = bx * 256 + w * 64;  // this wave's 64 q-rows

  const unsigned short* qp = q + ((long)bh * S_ + qbase) * 64;
  short8 aq0[4], aq1[4];
#pragma unroll
  for (int qb = 0; qb < 4; qb++) {
    aq0[qb] = *(const short8*)(qp + (qb * 16 + li) * 64 + g * 8);
    aq1[qb] = *(const short8*)(qp + (qb * 16 + li) * 64 + 32 + g * 8);
  }
  // mask word for (row=qbase+qb*16+li, kt): mpb[qb*1024 + kt*4]
  const unsigned int* mpb = mpk + ((long)(b * S_ + qbase + li) * 16) * 4 + g;

  const unsigned short* kbase = k + (long)bh * S_ * 64;
  int kst[4], kgo[4];
#pragma unroll
  for (int p = 0; p < 4; p++) {
    int e = (p * 256 + tid) * 8;
    int kr = e >> 6, kc = e & 63;
    kst[p] = kr * 72 + kc;
    kgo[p] = kr * 64 + kc;
  }

  float lsum[4] = {0.f, 0.f, 0.f, 0.f};
  short8 kreg[4];
#pragma unroll
  for (int p = 0; p < 4; p++) kreg[p] = *(const short8*)(kbase + kgo[p]);
  unsigned int mbn[4];
#pragma unroll
  for (int qb = 0; qb < 4; qb++) mbn[qb] = mpb[qb * 1024];

  for (int kt = 0; kt < 16; ++kt) {
    __syncthreads();
#pragma unroll
    for (int p = 0; p < 4; p++) *(short8*)(&k_lds[kst[p]]) = kreg[p];
    unsigned int mb[4];
#pragma unroll
    for (int qb = 0; qb < 4; qb++) mb[qb] = mbn[qb];
    if (kt < 15) {
#pragma unroll
      for (int p = 0; p < 4; p++)
        kreg[p] = *(const short8*)(kbase + (kt + 1) * 8192 + kgo[p]);
#pragma unroll
      for (int qb = 0; qb < 4; qb++) mbn[qb] = mpb[qb * 1024 + (kt + 1) * 4];
    }
    __syncthreads();
#pragma unroll
    for (int nb = 0; nb < 8; nb++) {
      short8 b0 = *(const short8*)(&k_lds[(nb * 16 + li) * 72 + g * 8]);
      short8 b1 = *(const short8*)(&k_lds[(nb * 16 + li) * 72 + 32 + g * 8]);
      f32x4 s0 = (f32x4){0.f, 0.f, 0.f, 0.f};
      f32x4 s1 = (f32x4){0.f, 0.f, 0.f, 0.f};
      f32x4 s2 = (f32x4){0.f, 0.f, 0.f, 0.f};
      f32x4 s3 = (f32x4){0.f, 0.f, 0.f, 0.f};
      __builtin_amdgcn_s_setprio(1);
      s0 = __builtin_amdgcn_mfma_f32_16x16x32_bf16(b0, aq0[0], s0, 0, 0, 0);
      s0 = __builtin_amdgcn_mfma_f32_16x16x32_bf16(b1, aq1[0], s0, 0, 0, 0);
      s1 = __builtin_amdgcn_mfma_f32_16x16x32_bf16(b0, aq0[1], s1, 0, 0, 0);
      s1 = __builtin_amdgcn_mfma_f32_16x16x32_bf16(b1, aq1[1], s1, 0, 0, 0);
      s2 = __builtin_amdgcn_mfma_f32_16x16x32_bf16(b0, aq0[2], s2, 0, 0, 0);
      s2 = __builtin_amdgcn_mfma_f32_16x16x32_bf16(b1, aq1[2], s2, 0, 0, 0);
      s3 = __builtin_amdgcn_mfma_f32_16x16x32_bf16(b0, aq0[3], s3, 0, 0, 0);
      s3 = __builtin_amdgcn_mfma_f32_16x16x32_bf16(b1, aq1[3], s3, 0, 0, 0);
      __builtin_amdgcn_s_setprio(0);
#pragma unroll
      for (int r = 0; r < 4; r++) {
        int bi = nb * 4 + r;
        lsum[0] += __expf(s0[r] * 0.125f + (((mb[0] >> bi) & 1u) ? 0.f : -1e9f));
        lsum[1] += __expf(s1[r] * 0.125f + (((mb[1] >> bi) & 1u) ? 0.f : -1e9f));
        lsum[2] += __expf(s2[r] * 0.125f + (((mb[2] >> bi) & 1u) ? 0.f : -1e9f));
        lsum[3] += __expf(s3[r] * 0.125f + (((mb[3] >> bi) & 1u) ? 0.f : -1e9f));
      }
    }
  }
#pragma unroll
  for (int qb = 0; qb < 4; qb++) {
    float v = lsum[qb];
    v += __shfl_xor(v, 16);
    v += __shfl_xor(v, 32);
    if (lane < 16)
      linvb[(long)bh * S_ + qbase + qb * 16 + li] = (v > 0.f) ? 1.0f / v : 0.f;
  }
}

// -------- pass 2: probs + PV (r7 structure, linv precomputed) --------------
__global__ __launch_bounds__(256, 4) void attn_kernel(
    const unsigned short* __restrict__ q,    // (BH,S,64)
    const unsigned short* __restrict__ k,    // (BH,S,64)
    const unsigned short* __restrict__ vt,   // (BH,64,S) plain transposed
    const unsigned int* __restrict__ mpk,    // packed mask
    const float* __restrict__ linvb,         // (BH,S)
    float* __restrict__ attn,                // (BH,S,S) f32
    unsigned short* __restrict__ ctx) {      // (B,S,D) bf16
  __shared__ unsigned short k_lds[128 * 72];   // [key][dd] pitch 72
  __shared__ unsigned short vt_lds[64 * 136];  // [dd][pi-key] pitch 136
  const int tid = threadIdx.x;
  const int lane = tid & 63, wid = tid >> 6;
  const int g = lane >> 4, li = lane & 15;
  // XCD-cluster swizzle (bijective): 8 heads per XCD
  const int p0 = blockIdx.x + 32 * blockIdx.y;
  const int xcd = p0 & 7, q8 = p0 >> 3;
  const int bx = q8 & 31;
  const int bh = xcd * 8 + (q8 >> 5);
  const int b = bh >> 4, h = bh & 15;
  const int qw = bx * 64 + wid * 16;
  const int qs = qw + li;  // per-lane score row

  const unsigned short* qp = q + ((long)bh * S_ + qw) * 64;
  const short8 aq0 = *(const short8*)(qp + li * 64 + g * 8);
  const short8 aq1 = *(const short8*)(qp + li * 64 + 32 + g * 8);
  const unsigned int* mp = mpk + (((long)b * S_ + qs) * 16) * 4 + g;
  const float linv = linvb[(long)bh * S_ + qs];

  const unsigned short* kbase = k + (long)bh * S_ * 64;
  const unsigned short* vbase = vt + (long)bh * 64 * S_;
  int kst[4], kgo[4], vst[4], vgo[4];
#pragma unroll
  for (int p = 0; p < 4; p++) {
    int e = (p * 256 + tid) * 8;
    int krr = e >> 6, kcc = e & 63;    // K tile 128x64
    kst[p] = krr * 72 + kcc;
    kgo[p] = krr * 64 + kcc;
    int vrr = e >> 7, vcc = e & 127;   // V tile 64x128
    // pi-permuted store base within 32-key chunk
    int c0 = ((vcc >> 5) << 5) + ((vcc & 8) << 1) + ((vcc & 16) >> 2);
    vst[p] = vrr * 136 + c0;
    vgo[p] = vrr * S_ + vcc;
  }

  f32x4 c[4];
#pragma unroll
  for (int i = 0; i < 4; i++) c[i] = (f32x4){0.f, 0.f, 0.f, 0.f};

  short8 kreg[4], vreg[4];
#pragma unroll
  for (int p = 0; p < 4; p++) {
    kreg[p] = *(const short8*)(kbase + kgo[p]);
    vreg[p] = *(const short8*)(vbase + vgo[p]);
  }
  unsigned int mb_n = mp[0];
  for (int kt = 0; kt < 16; ++kt) {
    __syncthreads();
#pragma unroll
    for (int p = 0; p < 4; p++) {
      *(short8*)(&k_lds[kst[p]]) = kreg[p];
      // pi-permuted V store: split short8 into two b64 halves
      ushort4* vh = (ushort4*)&vreg[p];
      *(ushort4*)(&vt_lds[vst[p]]) = vh[0];
      *(ushort4*)(&vt_lds[vst[p] + 8]) = vh[1];
    }
    unsigned int mb = mb_n;
    if (kt < 15) {
#pragma unroll
      for (int p = 0; p < 4; p++) {
        kreg[p] = *(const short8*)(kbase + (kt + 1) * 8192 + kgo[p]);
        vreg[p] = *(const short8*)(vbase + (kt + 1) * 128 + vgo[p]);
      }
      mb_n = mp[(kt + 1) * 4];
    }
    __syncthreads();
    float* arow = attn + ((long)bh * S_ + qs) * S_ + kt * 128;
    short8 pu2[4];  // per-lane P fragments, pi-key order
#pragma unroll
    for (int nb = 0; nb < 8; nb++) {
      short8 b0 = *(const short8*)(&k_lds[(nb * 16 + li) * 72 + g * 8]);
      short8 b1 = *(const short8*)(&k_lds[(nb * 16 + li) * 72 + 32 + g * 8]);
      f32x4 s = (f32x4){0.f, 0.f, 0.f, 0.f};
      __builtin_amdgcn_s_setprio(1);
      s = __builtin_amdgcn_mfma_f32_16x16x32_bf16(b0, aq0, s, 0, 0, 0);
      s = __builtin_amdgcn_mfma_f32_16x16x32_bf16(b1, aq1, s, 0, 0, 0);
      __builtin_amdgcn_s_setprio(0);
      f32x4 pf;
      ushort4 pu;
#pragma unroll
      for (int r = 0; r < 4; r++) {
        float sc = s[r] * 0.125f + (((mb >> (nb * 4 + r)) & 1u) ? 0.f : -1e9f);
        float pv = __expf(sc) * linv;
        pf[r] = pv;
        pu[r] = f2b(pv);
      }
      __builtin_nontemporal_store(pf, (f32x4*)(arow + nb * 16 + g * 4));
      ((ushort4*)&pu2[nb >> 1])[nb & 1] = pu;
    }
    __builtin_amdgcn_s_setprio(1);
#pragma unroll
    for (int kc = 0; kc < 4; kc++) {
      short8 ap = pu2[kc];
#pragma unroll
      for (int nb2 = 0; nb2 < 4; nb2++) {
        short8 bv =
            *(const short8*)(&vt_lds[(nb2 * 16 + li) * 136 + kc * 32 + g * 8]);
        c[nb2] = __builtin_amdgcn_mfma_f32_16x16x32_bf16(ap, bv, c[nb2], 0, 0, 0);
      }
    }
    __builtin_amdgcn_s_setprio(0);
  }

#pragma unroll
  for (int nb2 = 0; nb2 < 4; nb2++) {
#pragma unroll
    for (int j = 0; j < 4; j++) {
      int qrow = qw + g * 4 + j;
      ctx[((long)(b * S_ + qrow)) * D_ + h * 64 + nb2 * 16 + li] = f2b(c[nb2][j]);
    }
  }
}

extern "C" void kernel_launch(void* const* d_in, const int* in_sizes, int n_in,
                              void* d_out, int out_size, void* d_ws, size_t ws_size,
                              hipStream_t stream) {
  const float* Q = (const float*)d_in[0];
  const float* K = (const float*)d_in[1];
  const float* V = (const float*)d_in[2];
  const int* mask = (const int*)d_in[3];
  const float* Wq = (const float*)d_in[4];
  const float* bq = (const float*)d_in[5];
  const float* Wk = (const float*)d_in[6];
  const float* bk = (const float*)d_in[7];
  const float* Wv = (const float*)d_in[8];
  const float* bv = (const float*)d_in[9];
  const float* Wo = (const float*)d_in[10];
  const float* bo = (const float*)d_in[11];

  float* out = (float*)d_out;  // (B,S,D) f32
  float* attn = out + TSZ;     // (B,H,S,S) f32
  // packed mask (2 MB) lives in the out region; overwritten by final GEMM
  unsigned int* mpack = (unsigned int*)d_out;

  unsigned short* ws = (unsigned short*)d_ws;
  unsigned short* qh = ws;              // (BH,S,64) bf16
  unsigned short* kh = ws + TSZ;        // (BH,S,64)
  unsigned short* vt = ws + 2 * TSZ;    // (BH,64,S)
  unsigned short* ctx = ws + 3 * TSZ;   // (B,S,D) bf16
  unsigned short* qbf = ws + 4 * TSZ;   // bf16 inputs
  unsigned short* kbf = ws + 5 * TSZ;
  unsigned short* vbf = ws + 6 * TSZ;
  unsigned short* wtq = ws + 7 * TSZ;
  unsigned short* wtk = wtq + 1048576;
  unsigned short* wtv = wtk + 1048576;
  unsigned short* wto = wtv + 1048576;
  float* linvb = (float*)(wto + 1048576);  // (BH,S) = 512 KB

  dim3 bb(256);
  cvt3m<<<12800, bb, 0, stream>>>(Q, K, V, mask, qbf, kbf, vbf, mpack);
  transpose_w4<<<dim3(16, 16, 4), bb, 0, stream>>>(Wq, Wk, Wv, Wo, wtq, wtk,
                                                   wtv, wto);
  qkv_gemm<<<dim3(64, 8, 3), bb, 0, stream>>>(qbf, kbf, vbf, wtq, wtk, wtv, bq,
                                              bk, bv, qh, kh, vt);
  lsum_kernel<<<dim3(8, 64), bb, 0, stream>>>(qh, kh, mpack, linvb);
  attn_kernel<<<dim3(32, 64), bb, 0, stream>>>(qh, kh, vt, mpack, linvb, attn,
                                               ctx);
  wo_gemm<<<dim3(64, 8), bb, 0, stream>>>(ctx, wto, bo, out);
}

// Round 13
// 505.607 us; speedup vs baseline: 1.1118x; 1.1118x over previous
//
#include <hip/hip_runtime.h>
#include <hip/hip_bf16.h>

#define B_ 4
#define S_ 2048
#define D_ 1024
#define H_ 16
#define TSZ 8388608L  // B*S*D elements
#define QSCALE 0.18033688f  // 0.125 * log2(e), folded into Q projection

typedef short short8 __attribute__((ext_vector_type(8)));
typedef float f32x4 __attribute__((ext_vector_type(4)));

__device__ inline unsigned short f2b(float f) {
  __hip_bfloat16 h = __float2bfloat16(f);
  return __builtin_bit_cast(unsigned short, h);
}
// async global->LDS, 16 bytes per lane; LDS dest must be wave-uniform base
__device__ inline void gld16(const unsigned short* g, unsigned short* l) {
  __builtin_amdgcn_global_load_lds(
      (const __attribute__((address_space(1))) void*)g,
      (__attribute__((address_space(3))) void*)l, 16, 0, 0);
}

// ---- fused prep: f32->bf16 cvt (QKV) + mask bit-pack + weight transpose ----
// blocks 0..12287: cvt; 12288..12799: mask_pack; 12800..13823: transpose_w x4
__global__ __launch_bounds__(256) void prep_all(
    const float* __restrict__ Q, const float* __restrict__ K,
    const float* __restrict__ V, const int* __restrict__ mask,
    const float* __restrict__ W0, const float* __restrict__ W1,
    const float* __restrict__ W2, const float* __restrict__ W3,
    unsigned short* __restrict__ qo, unsigned short* __restrict__ ko,
    unsigned short* __restrict__ vo, unsigned int* __restrict__ mp,
    unsigned short* __restrict__ T0, unsigned short* __restrict__ T1,
    unsigned short* __restrict__ T2, unsigned short* __restrict__ T3) {
  __shared__ unsigned short t[64 * 72];  // transpose staging
  const int tid = threadIdx.x;
  if (blockIdx.x < 12288) {
    int seg = blockIdx.x >> 12;
    long i = ((long)(blockIdx.x & 4095) * 256 + tid) * 8;
    const float* in = seg == 0 ? Q : seg == 1 ? K : V;
    unsigned short* out = seg == 0 ? qo : seg == 1 ? ko : vo;
    float4 a = *(const float4*)(in + i);
    float4 b = *(const float4*)(in + i + 4);
    short8 u;
    u[0] = (short)f2b(a.x); u[1] = (short)f2b(a.y);
    u[2] = (short)f2b(a.z); u[3] = (short)f2b(a.w);
    u[4] = (short)f2b(b.x); u[5] = (short)f2b(b.y);
    u[6] = (short)f2b(b.z); u[7] = (short)f2b(b.w);
    *(short8*)(out + i) = u;
  } else if (blockIdx.x < 12800) {
    long tt = (long)(blockIdx.x - 12288) * 256 + tid;  // row*16 + kt
    const int4* p = (const int4*)(mask + (tt >> 4) * (long)S_ + (tt & 15) * 128);
    unsigned int w0 = 0, w1 = 0, w2 = 0, w3 = 0;
#pragma unroll
    for (int c = 0; c < 32; c++) {
      int4 v = p[c];
#pragma unroll
      for (int e = 0; e < 4; e++) {
        int k = c * 4 + e;
        int val = e == 0 ? v.x : e == 1 ? v.y : e == 2 ? v.z : v.w;
        int nb = k >> 4, p16 = k & 15;
        int gg = p16 >> 2, r = p16 & 3;
        unsigned bit = ((unsigned)val & 1u) << (nb * 4 + r);
        if (gg == 0) w0 |= bit; else if (gg == 1) w1 |= bit;
        else if (gg == 2) w2 |= bit; else w3 |= bit;
      }
    }
    *(uint4*)(mp + tt * 4) = make_uint4(w0, w1, w2, w3);
  } else {
    int tz = blockIdx.x - 12800;
    int z = tz >> 8, rem = tz & 255;
    const float* W = z == 0 ? W0 : z == 1 ? W1 : z == 2 ? W2 : W3;
    unsigned short* Wt = z == 0 ? T0 : z == 1 ? T1 : z == 2 ? T2 : T3;
    const int k0 = (rem >> 4) * 64, n0 = (rem & 15) * 64;
#pragma unroll
    for (int p = 0; p < 4; p++) {
      int e = (p * 256 + tid) * 4;
      int r = e >> 6, c = e & 63;
      float4 v = *(const float4*)(W + (long)(k0 + r) * D_ + n0 + c);
      ushort4 u;
      u.x = f2b(v.x); u.y = f2b(v.y); u.z = f2b(v.z); u.w = f2b(v.w);
      *(ushort4*)(&t[r * 72 + c]) = u;
    }
    __syncthreads();
#pragma unroll
    for (int p = 0; p < 2; p++) {
      int e = (p * 256 + tid) * 8;
      int n = e >> 6, kc = e & 63;
      short8 x;
#pragma unroll
      for (int i = 0; i < 8; i++) x[i] = (short)t[(kc + i) * 72 + n];
      *(short8*)(Wt + (long)(n0 + n) * D_ + k0 + kc) = x;
    }
  }
}

// ---------------- fused QKV projection GEMM --------------------------------
// z=0: Q->qh (head-major, PRESCALED by QSCALE), z=1: K->kh, z=2: V->vt
__global__ __launch_bounds__(256) void qkv_gemm(
    const unsigned short* __restrict__ qa, const unsigned short* __restrict__ ka,
    const unsigned short* __restrict__ va, const unsigned short* __restrict__ wq,
    const unsigned short* __restrict__ wk, const unsigned short* __restrict__ wv,
    const float* __restrict__ bqp, const float* __restrict__ bkp,
    const float* __restrict__ bvp, unsigned short* __restrict__ qo,
    unsigned short* __restrict__ ko, unsigned short* __restrict__ vo) {
  __shared__ unsigned short Asm[128 * 32];
  __shared__ unsigned short Bsm[128 * 32];
  const int z = blockIdx.z;
  const unsigned short* A = z == 0 ? qa : z == 1 ? ka : va;
  const unsigned short* Wt = z == 0 ? wq : z == 1 ? wk : wv;
  const float* bias = z == 0 ? bqp : z == 1 ? bkp : bvp;
  unsigned short* outp = z == 0 ? qo : z == 1 ? ko : vo;
  const float osc = (z == 0) ? QSCALE : 1.0f;
  const int tid = threadIdx.x;
  const int lane = tid & 63, wid = tid >> 6;
  const int g = lane >> 4, li = lane & 15;
  const int wm = wid >> 1, wn = wid & 1;
  const long bm = (long)blockIdx.x * 128;
  const long bn = (long)blockIdx.y * 128;

  f32x4 acc[4][4];
#pragma unroll
  for (int i = 0; i < 4; i++)
#pragma unroll
    for (int j = 0; j < 4; j++) acc[i][j] = (f32x4){0.f, 0.f, 0.f, 0.f};

  for (int kt = 0; kt < 32; ++kt) {
    const int k0 = kt * 32;
    __syncthreads();
#pragma unroll
    for (int p = 0; p < 2; p++) {
      int ci = p * 256 + wid * 64 + lane;
      int r = ci >> 2, c = (ci & 3) * 8;
      gld16(A + (bm + r) * 1024L + k0 + c, &Asm[(p * 256 + wid * 64) * 8]);
      gld16(Wt + (bn + r) * 1024L + k0 + c, &Bsm[(p * 256 + wid * 64) * 8]);
    }
    __syncthreads();
    short8 af[4], bf[4];
#pragma unroll
    for (int i = 0; i < 4; i++)
      af[i] = *(const short8*)(&Asm[(wm * 64 + i * 16 + li) * 32 + g * 8]);
#pragma unroll
    for (int i = 0; i < 4; i++)
      bf[i] = *(const short8*)(&Bsm[(wn * 64 + i * 16 + li) * 32 + g * 8]);
#pragma unroll
    for (int i = 0; i < 4; i++)
#pragma unroll
      for (int j = 0; j < 4; j++)
        acc[i][j] =
            __builtin_amdgcn_mfma_f32_16x16x32_bf16(af[i], bf[j], acc[i][j], 0, 0, 0);
  }

#pragma unroll
  for (int i = 0; i < 4; i++) {
    int row0 = (int)bm + wm * 64 + i * 16 + g * 4;
#pragma unroll
    for (int j = 0; j < 4; j++) {
      int col = (int)bn + wn * 64 + j * 16 + li;
      float bvv = bias[col];
      if (z == 2) {
        int b = row0 >> 11, s0 = row0 & 2047;
        int h = col >> 6, dd = col & 63;
        ushort4 u;
#pragma unroll
        for (int jj = 0; jj < 4; jj++) u[jj] = f2b(acc[i][j][jj] + bvv);
        *(ushort4*)(outp + ((long)(b * H_ + h) * 64 + dd) * S_ + s0) = u;
      } else {
#pragma unroll
        for (int jj = 0; jj < 4; jj++) {
          int row = row0 + jj;
          int b = row >> 11, s = row & 2047;
          int h = col >> 6, dd = col & 63;
          outp[(((long)(b * H_ + h)) * S_ + s) * 64 + dd] =
              f2b((acc[i][j][jj] + bvv) * osc);
        }
      }
    }
  }
}

// ---------------- output GEMM: out = ctx @ Wo^T + bo (f32 out) -------------
__global__ __launch_bounds__(256) void wo_gemm(
    const unsigned short* __restrict__ A, const unsigned short* __restrict__ Wt,
    const float* __restrict__ bias, float* __restrict__ out) {
  __shared__ unsigned short Asm[128 * 32];
  __shared__ unsigned short Bsm[128 * 32];
  const int tid = threadIdx.x;
  const int lane = tid & 63, wid = tid >> 6;
  const int g = lane >> 4, li = lane & 15;
  const int wm = wid >> 1, wn = wid & 1;
  const long bm = (long)blockIdx.x * 128;
  const long bn = (long)blockIdx.y * 128;

  f32x4 acc[4][4];
#pragma unroll
  for (int i = 0; i < 4; i++)
#pragma unroll
    for (int j = 0; j < 4; j++) acc[i][j] = (f32x4){0.f, 0.f, 0.f, 0.f};

  for (int kt = 0; kt < 32; ++kt) {
    const int k0 = kt * 32;
    __syncthreads();
#pragma unroll
    for (int p = 0; p < 2; p++) {
      int ci = p * 256 + wid * 64 + lane;
      int r = ci >> 2, c = (ci & 3) * 8;
      gld16(A + (bm + r) * 1024L + k0 + c, &Asm[(p * 256 + wid * 64) * 8]);
      gld16(Wt + (bn + r) * 1024L + k0 + c, &Bsm[(p * 256 + wid * 64) * 8]);
    }
    __syncthreads();
    short8 af[4], bf[4];
#pragma unroll
    for (int i = 0; i < 4; i++)
      af[i] = *(const short8*)(&Asm[(wm * 64 + i * 16 + li) * 32 + g * 8]);
#pragma unroll
    for (int i = 0; i < 4; i++)
      bf[i] = *(const short8*)(&Bsm[(wn * 64 + i * 16 + li) * 32 + g * 8]);
#pragma unroll
    for (int i = 0; i < 4; i++)
#pragma unroll
      for (int j = 0; j < 4; j++)
        acc[i][j] =
            __builtin_amdgcn_mfma_f32_16x16x32_bf16(af[i], bf[j], acc[i][j], 0, 0, 0);
  }

#pragma unroll
  for (int i = 0; i < 4; i++) {
    int row0 = (int)bm + wm * 64 + i * 16 + g * 4;
#pragma unroll
    for (int j = 0; j < 4; j++) {
      int col = (int)bn + wn * 64 + j * 16 + li;
      float bvv = bias[col];
#pragma unroll
      for (int jj = 0; jj < 4; jj++)
        out[(long)(row0 + jj) * 1024 + col] = acc[i][j][jj] + bvv;
    }
  }
}

// -------- fused attn (r7 structure): K+V LDS, P-in-reg, exp2 softmax -------
__global__ __launch_bounds__(256, 4) void attn_kernel(
    const unsigned short* __restrict__ q,    // (BH,S,64) prescaled
    const unsigned short* __restrict__ k,    // (BH,S,64)
    const unsigned short* __restrict__ vt,   // (BH,64,S)
    const unsigned int* __restrict__ mpk,    // packed mask
    float* __restrict__ attn,                // (BH,S,S) f32
    unsigned short* __restrict__ ctx) {      // (B,S,D) bf16
  __shared__ unsigned short k_lds[128 * 72];   // [key][dd] pitch 72
  __shared__ unsigned short vt_lds[64 * 136];  // [dd][pi-key] pitch 136
  const int tid = threadIdx.x;
  const int lane = tid & 63, wid = tid >> 6;
  const int g = lane >> 4, li = lane & 15;
  // XCD-cluster swizzle (bijective): 8 heads per XCD
  const int p0 = blockIdx.x + 32 * blockIdx.y;
  const int xcd = p0 & 7, q8 = p0 >> 3;
  const int bx = q8 & 31;
  const int bh = xcd * 8 + (q8 >> 5);
  const int b = bh >> 4, h = bh & 15;
  const int qw = bx * 64 + wid * 16;
  const int qs = qw + li;  // per-lane score row

  const unsigned short* qp = q + ((long)bh * S_ + qw) * 64;
  const short8 aq0 = *(const short8*)(qp + li * 64 + g * 8);
  const short8 aq1 = *(const short8*)(qp + li * 64 + 32 + g * 8);
  const unsigned int* mp = mpk + (((long)b * S_ + qs) * 16) * 4 + g;

  const unsigned short* kbase = k + (long)bh * S_ * 64;
  const unsigned short* vbase = vt + (long)bh * 64 * S_;
  // precomputed per-thread offsets
  int kst[4], kgo[4], vst[4], vgo[4];
#pragma unroll
  for (int p = 0; p < 4; p++) {
    int e = (p * 256 + tid) * 8;
    int krr = e >> 6, kcc = e & 63;    // K tile 128x64
    kst[p] = krr * 72 + kcc;
    kgo[p] = krr * 64 + kcc;
    int vrr = e >> 7, vcc = e & 127;   // V tile 64x128
    // pi-permuted store base within 32-key chunk
    int c0 = ((vcc >> 5) << 5) + ((vcc & 8) << 1) + ((vcc & 16) >> 2);
    vst[p] = vrr * 136 + c0;
    vgo[p] = vrr * S_ + vcc;
  }

  // ---- pass 1: denominators ----
  float lsum = 0.f;
  short8 kreg[4];
#pragma unroll
  for (int p = 0; p < 4; p++)
    kreg[p] = *(const short8*)(kbase + kgo[p]);
  unsigned int mb_n = mp[0];
  for (int kt = 0; kt < 16; ++kt) {
    __syncthreads();
#pragma unroll
    for (int p = 0; p < 4; p++)
      *(short8*)(&k_lds[kst[p]]) = kreg[p];
    unsigned int mb = mb_n;
    if (kt < 15) {
#pragma unroll
      for (int p = 0; p < 4; p++)
        kreg[p] = *(const short8*)(kbase + ((long)(kt + 1) * 128) * 64 + kgo[p]);
      mb_n = mp[(kt + 1) * 4];
    }
    __syncthreads();
#pragma unroll
    for (int nb = 0; nb < 8; nb++) {
      short8 b0 = *(const short8*)(&k_lds[(nb * 16 + li) * 72 + g * 8]);
      short8 b1 = *(const short8*)(&k_lds[(nb * 16 + li) * 72 + 32 + g * 8]);
      f32x4 s = (f32x4){0.f, 0.f, 0.f, 0.f};
      __builtin_amdgcn_s_setprio(1);
      s = __builtin_amdgcn_mfma_f32_16x16x32_bf16(b0, aq0, s, 0, 0, 0);
      s = __builtin_amdgcn_mfma_f32_16x16x32_bf16(b1, aq1, s, 0, 0, 0);
      __builtin_amdgcn_s_setprio(0);
#pragma unroll
      for (int r = 0; r < 4; r++) {
        float ev = exp2f(s[r]);
        lsum += (((mb >> (nb * 4 + r)) & 1u) ? ev : 0.f);
      }
    }
  }
  lsum += __shfl_xor(lsum, 16);
  lsum += __shfl_xor(lsum, 32);
  const float linv = (lsum > 0.f) ? 1.0f / lsum : 0.f;

  // ---- pass 2: probs + PV ----
  f32x4 c[4];
#pragma unroll
  for (int i = 0; i < 4; i++) c[i] = (f32x4){0.f, 0.f, 0.f, 0.f};

  short8 vreg[4];
#pragma unroll
  for (int p = 0; p < 4; p++) {
    kreg[p] = *(const short8*)(kbase + kgo[p]);
    vreg[p] = *(const short8*)(vbase + vgo[p]);
  }
  mb_n = mp[0];
  for (int kt = 0; kt < 16; ++kt) {
    __syncthreads();
#pragma unroll
    for (int p = 0; p < 4; p++) {
      *(short8*)(&k_lds[kst[p]]) = kreg[p];
      // pi-permuted V store: split short8 into two b64 halves
      ushort4* vh = (ushort4*)&vreg[p];
      *(ushort4*)(&vt_lds[vst[p]]) = vh[0];
      *(ushort4*)(&vt_lds[vst[p] + 8]) = vh[1];
    }
    unsigned int mb = mb_n;
    if (kt < 15) {
#pragma unroll
      for (int p = 0; p < 4; p++) {
        kreg[p] = *(const short8*)(kbase + ((long)(kt + 1) * 128) * 64 + kgo[p]);
        vreg[p] = *(const short8*)(vbase + (kt + 1) * 128 + vgo[p]);
      }
      mb_n = mp[(kt + 1) * 4];
    }
    __syncthreads();
    float* arow = attn + ((long)bh * S_ + qs) * S_ + kt * 128;
    short8 pu2[4];  // per-lane P fragments, pi-key order
#pragma unroll
    for (int nb = 0; nb < 8; nb++) {
      short8 b0 = *(const short8*)(&k_lds[(nb * 16 + li) * 72 + g * 8]);
      short8 b1 = *(const short8*)(&k_lds[(nb * 16 + li) * 72 + 32 + g * 8]);
      f32x4 s = (f32x4){0.f, 0.f, 0.f, 0.f};
      __builtin_amdgcn_s_setprio(1);
      s = __builtin_amdgcn_mfma_f32_16x16x32_bf16(b0, aq0, s, 0, 0, 0);
      s = __builtin_amdgcn_mfma_f32_16x16x32_bf16(b1, aq1, s, 0, 0, 0);
      __builtin_amdgcn_s_setprio(0);
      f32x4 pf;
      ushort4 pu;
#pragma unroll
      for (int r = 0; r < 4; r++) {
        float ev = exp2f(s[r]) * linv;
        float pv = (((mb >> (nb * 4 + r)) & 1u) ? ev : 0.f);
        pf[r] = pv;
        pu[r] = f2b(pv);
      }
      __builtin_nontemporal_store(pf, (f32x4*)(arow + nb * 16 + g * 4));
      ((ushort4*)&pu2[nb >> 1])[nb & 1] = pu;
    }
    __builtin_amdgcn_s_setprio(1);
#pragma unroll
    for (int kc = 0; kc < 4; kc++) {
      short8 ap = pu2[kc];
#pragma unroll
      for (int nb2 = 0; nb2 < 4; nb2++) {
        short8 bv =
            *(const short8*)(&vt_lds[(nb2 * 16 + li) * 136 + kc * 32 + g * 8]);
        c[nb2] = __builtin_amdgcn_mfma_f32_16x16x32_bf16(ap, bv, c[nb2], 0, 0, 0);
      }
    }
    __builtin_amdgcn_s_setprio(0);
  }

#pragma unroll
  for (int nb2 = 0; nb2 < 4; nb2++) {
#pragma unroll
    for (int j = 0; j < 4; j++) {
      int qrow = qw + g * 4 + j;
      ctx[((long)(b * S_ + qrow)) * D_ + h * 64 + nb2 * 16 + li] = f2b(c[nb2][j]);
    }
  }
}

extern "C" void kernel_launch(void* const* d_in, const int* in_sizes, int n_in,
                              void* d_out, int out_size, void* d_ws, size_t ws_size,
                              hipStream_t stream) {
  const float* Q = (const float*)d_in[0];
  const float* K = (const float*)d_in[1];
  const float* V = (const float*)d_in[2];
  const int* mask = (const int*)d_in[3];
  const float* Wq = (const float*)d_in[4];
  const float* bq = (const float*)d_in[5];
  const float* Wk = (const float*)d_in[6];
  const float* bk = (const float*)d_in[7];
  const float* Wv = (const float*)d_in[8];
  const float* bv = (const float*)d_in[9];
  const float* Wo = (const float*)d_in[10];
  const float* bo = (const float*)d_in[11];

  float* out = (float*)d_out;  // (B,S,D) f32
  float* attn = out + TSZ;     // (B,H,S,S) f32
  // packed mask (2 MB) lives in the out region; overwritten by final GEMM
  unsigned int* mpack = (unsigned int*)d_out;

  unsigned short* ws = (unsigned short*)d_ws;
  unsigned short* qh = ws;              // (BH,S,64) bf16 (prescaled)
  unsigned short* kh = ws + TSZ;        // (BH,S,64)
  unsigned short* vt = ws + 2 * TSZ;    // (BH,64,S)
  unsigned short* ctx = ws + 3 * TSZ;   // (B,S,D) bf16
  unsigned short* qbf = ws + 4 * TSZ;   // bf16 inputs
  unsigned short* kbf = ws + 5 * TSZ;
  unsigned short* vbf = ws + 6 * TSZ;
  unsigned short* wtq = ws + 7 * TSZ;
  unsigned short* wtk = wtq + 1048576;
  unsigned short* wtv = wtk + 1048576;
  unsigned short* wto = wtv + 1048576;

  dim3 bb(256);
  prep_all<<<13824, bb, 0, stream>>>(Q, K, V, mask, Wq, Wk, Wv, Wo, qbf, kbf,
                                     vbf, mpack, wtq, wtk, wtv, wto);
  qkv_gemm<<<dim3(64, 8, 3), bb, 0, stream>>>(qbf, kbf, vbf, wtq, wtk, wtv, bq,
                                              bk, bv, qh, kh, vt);
  attn_kernel<<<dim3(32, 64), bb, 0, stream>>>(qh, kh, vt, mpack, attn, ctx);
  wo_gemm<<<dim3(64, 8), bb, 0, stream>>>(ctx, wto, bo, out);
}

// Round 14
// 475.061 us; speedup vs baseline: 1.1833x; 1.0643x over previous
//
#include <hip/hip_runtime.h>
#include <hip/hip_bf16.h>

#define B_ 4
#define S_ 2048
#define D_ 1024
#define H_ 16
#define TSZ 8388608L  // B*S*D elements

typedef short short8 __attribute__((ext_vector_type(8)));
typedef float f32x4 __attribute__((ext_vector_type(4)));

__device__ inline unsigned short f2b(float f) {
  __hip_bfloat16 h = __float2bfloat16(f);
  return __builtin_bit_cast(unsigned short, h);
}
// async global->LDS, 16 bytes per lane; LDS dest must be wave-uniform base
__device__ inline void gld16(const unsigned short* g, unsigned short* l) {
  __builtin_amdgcn_global_load_lds(
      (const __attribute__((address_space(1))) void*)g,
      (__attribute__((address_space(3))) void*)l, 16, 0, 0);
}

// ---------------- mask pack: int32 (B,S,S) -> bitmask ----------------------
// word index = ((row*16 + kt)*4 + g), bit (nb*4+r) = mask[row][kt*128+nb*16+g*4+r]
__global__ __launch_bounds__(256) void mask_pack(const int* __restrict__ mask,
                                                 unsigned int* __restrict__ mp) {
  long t = (long)blockIdx.x * 256 + threadIdx.x;  // t = row*16 + kt
  const int4* p = (const int4*)(mask + (t >> 4) * (long)S_ + (t & 15) * 128);
  unsigned int w0 = 0, w1 = 0, w2 = 0, w3 = 0;
#pragma unroll
  for (int c = 0; c < 32; c++) {
    int4 v = p[c];
#pragma unroll
    for (int e = 0; e < 4; e++) {
      int k = c * 4 + e;
      int val = e == 0 ? v.x : e == 1 ? v.y : e == 2 ? v.z : v.w;
      int nb = k >> 4, p16 = k & 15;
      int gg = p16 >> 2, r = p16 & 3;
      unsigned bit = ((unsigned)val & 1u) << (nb * 4 + r);
      if (gg == 0) w0 |= bit; else if (gg == 1) w1 |= bit;
      else if (gg == 2) w2 |= bit; else w3 |= bit;
    }
  }
  *(uint4*)(mp + t * 4) = make_uint4(w0, w1, w2, w3);
}

// ---------------- f32 -> bf16 convert for Q,K,V (one launch) ---------------
__global__ __launch_bounds__(256) void cvt3(
    const float* __restrict__ Q, const float* __restrict__ K,
    const float* __restrict__ V, unsigned short* __restrict__ qo,
    unsigned short* __restrict__ ko, unsigned short* __restrict__ vo) {
  int seg = blockIdx.x >> 12;
  long i = ((long)(blockIdx.x & 4095) * 256 + threadIdx.x) * 8;
  const float* in = seg == 0 ? Q : seg == 1 ? K : V;
  unsigned short* out = seg == 0 ? qo : seg == 1 ? ko : vo;
  float4 a = *(const float4*)(in + i);
  float4 b = *(const float4*)(in + i + 4);
  short8 u;
  u[0] = (short)f2b(a.x); u[1] = (short)f2b(a.y);
  u[2] = (short)f2b(a.z); u[3] = (short)f2b(a.w);
  u[4] = (short)f2b(b.x); u[5] = (short)f2b(b.y);
  u[6] = (short)f2b(b.z); u[7] = (short)f2b(b.w);
  *(short8*)(out + i) = u;
}

// ---------------- weight transpose x4: W f32 [K][N] -> Wt bf16 [N][K] ------
__global__ __launch_bounds__(256) void transpose_w4(
    const float* __restrict__ W0, const float* __restrict__ W1,
    const float* __restrict__ W2, const float* __restrict__ W3,
    unsigned short* __restrict__ T0, unsigned short* __restrict__ T1,
    unsigned short* __restrict__ T2, unsigned short* __restrict__ T3) {
  __shared__ unsigned short t[64 * 72];  // [k][n] pitch 72
  const int z = blockIdx.z;
  const float* W = z == 0 ? W0 : z == 1 ? W1 : z == 2 ? W2 : W3;
  unsigned short* Wt = z == 0 ? T0 : z == 1 ? T1 : z == 2 ? T2 : T3;
  const int tid = threadIdx.x;
  const int k0 = blockIdx.x * 64, n0 = blockIdx.y * 64;
#pragma unroll
  for (int p = 0; p < 4; p++) {
    int e = (p * 256 + tid) * 4;
    int r = e >> 6, c = e & 63;
    float4 v = *(const float4*)(W + (long)(k0 + r) * D_ + n0 + c);
    ushort4 u;
    u.x = f2b(v.x); u.y = f2b(v.y); u.z = f2b(v.z); u.w = f2b(v.w);
    *(ushort4*)(&t[r * 72 + c]) = u;
  }
  __syncthreads();
#pragma unroll
  for (int p = 0; p < 2; p++) {
    int e = (p * 256 + tid) * 8;
    int n = e >> 6, kc = e & 63;
    short8 x;
#pragma unroll
    for (int i = 0; i < 8; i++) x[i] = (short)t[(kc + i) * 72 + n];
    *(short8*)(Wt + (long)(n0 + n) * D_ + k0 + kc) = x;
  }
}

// ---------------- fused QKV projection GEMM --------------------------------
// z=0: Q->qh (head-major), z=1: K->kh (head-major), z=2: V->vt (transposed)
__global__ __launch_bounds__(256) void qkv_gemm(
    const unsigned short* __restrict__ qa, const unsigned short* __restrict__ ka,
    const unsigned short* __restrict__ va, const unsigned short* __restrict__ wq,
    const unsigned short* __restrict__ wk, const unsigned short* __restrict__ wv,
    const float* __restrict__ bqp, const float* __restrict__ bkp,
    const float* __restrict__ bvp, unsigned short* __restrict__ qo,
    unsigned short* __restrict__ ko, unsigned short* __restrict__ vo) {
  __shared__ unsigned short Asm[128 * 32];
  __shared__ unsigned short Bsm[128 * 32];
  const int z = blockIdx.z;
  const unsigned short* A = z == 0 ? qa : z == 1 ? ka : va;
  const unsigned short* Wt = z == 0 ? wq : z == 1 ? wk : wv;
  const float* bias = z == 0 ? bqp : z == 1 ? bkp : bvp;
  unsigned short* outp = z == 0 ? qo : z == 1 ? ko : vo;
  const int tid = threadIdx.x;
  const int lane = tid & 63, wid = tid >> 6;
  const int g = lane >> 4, li = lane & 15;
  const int wm = wid >> 1, wn = wid & 1;
  const long bm = (long)blockIdx.x * 128;
  const long bn = (long)blockIdx.y * 128;

  f32x4 acc[4][4];
#pragma unroll
  for (int i = 0; i < 4; i++)
#pragma unroll
    for (int j = 0; j < 4; j++) acc[i][j] = (f32x4){0.f, 0.f, 0.f, 0.f};

  for (int kt = 0; kt < 32; ++kt) {
    const int k0 = kt * 32;
    __syncthreads();
#pragma unroll
    for (int p = 0; p < 2; p++) {
      int ci = p * 256 + wid * 64 + lane;
      int r = ci >> 2, c = (ci & 3) * 8;
      gld16(A + (bm + r) * 1024L + k0 + c, &Asm[(p * 256 + wid * 64) * 8]);
      gld16(Wt + (bn + r) * 1024L + k0 + c, &Bsm[(p * 256 + wid * 64) * 8]);
    }
    __syncthreads();
    short8 af[4], bf[4];
#pragma unroll
    for (int i = 0; i < 4; i++)
      af[i] = *(const short8*)(&Asm[(wm * 64 + i * 16 + li) * 32 + g * 8]);
#pragma unroll
    for (int i = 0; i < 4; i++)
      bf[i] = *(const short8*)(&Bsm[(wn * 64 + i * 16 + li) * 32 + g * 8]);
#pragma unroll
    for (int i = 0; i < 4; i++)
#pragma unroll
      for (int j = 0; j < 4; j++)
        acc[i][j] =
            __builtin_amdgcn_mfma_f32_16x16x32_bf16(af[i], bf[j], acc[i][j], 0, 0, 0);
  }

#pragma unroll
  for (int i = 0; i < 4; i++) {
    int row0 = (int)bm + wm * 64 + i * 16 + g * 4;
#pragma unroll
    for (int j = 0; j < 4; j++) {
      int col = (int)bn + wn * 64 + j * 16 + li;
      float bvv = bias[col];
      if (z == 2) {
        int b = row0 >> 11, s0 = row0 & 2047;
        int h = col >> 6, dd = col & 63;
        ushort4 u;
#pragma unroll
        for (int jj = 0; jj < 4; jj++) u[jj] = f2b(acc[i][j][jj] + bvv);
        *(ushort4*)(outp + ((long)(b * H_ + h) * 64 + dd) * S_ + s0) = u;
      } else {
#pragma unroll
        for (int jj = 0; jj < 4; jj++) {
          int row = row0 + jj;
          int b = row >> 11, s = row & 2047;
          int h = col >> 6, dd = col & 63;
          outp[(((long)(b * H_ + h)) * S_ + s) * 64 + dd] =
              f2b(acc[i][j][jj] + bvv);
        }
      }
    }
  }
}

// ---------------- output GEMM: out = ctx @ Wo^T + bo (f32 out) -------------
__global__ __launch_bounds__(256) void wo_gemm(
    const unsigned short* __restrict__ A, const unsigned short* __restrict__ Wt,
    const float* __restrict__ bias, float* __restrict__ out) {
  __shared__ unsigned short Asm[128 * 32];
  __shared__ unsigned short Bsm[128 * 32];
  const int tid = threadIdx.x;
  const int lane = tid & 63, wid = tid >> 6;
  const int g = lane >> 4, li = lane & 15;
  const int wm = wid >> 1, wn = wid & 1;
  const long bm = (long)blockIdx.x * 128;
  const long bn = (long)blockIdx.y * 128;

  f32x4 acc[4][4];
#pragma unroll
  for (int i = 0; i < 4; i++)
#pragma unroll
    for (int j = 0; j < 4; j++) acc[i][j] = (f32x4){0.f, 0.f, 0.f, 0.f};

  for (int kt = 0; kt < 32; ++kt) {
    const int k0 = kt * 32;
    __syncthreads();
#pragma unroll
    for (int p = 0; p < 2; p++) {
      int ci = p * 256 + wid * 64 + lane;
      int r = ci >> 2, c = (ci & 3) * 8;
      gld16(A + (bm + r) * 1024L + k0 + c, &Asm[(p * 256 + wid * 64) * 8]);
      gld16(Wt + (bn + r) * 1024L + k0 + c, &Bsm[(p * 256 + wid * 64) * 8]);
    }
    __syncthreads();
    short8 af[4], bf[4];
#pragma unroll
    for (int i = 0; i < 4; i++)
      af[i] = *(const short8*)(&Asm[(wm * 64 + i * 16 + li) * 32 + g * 8]);
#pragma unroll
    for (int i = 0; i < 4; i++)
      bf[i] = *(const short8*)(&Bsm[(wn * 64 + i * 16 + li) * 32 + g * 8]);
#pragma unroll
    for (int i = 0; i < 4; i++)
#pragma unroll
      for (int j = 0; j < 4; j++)
        acc[i][j] =
            __builtin_amdgcn_mfma_f32_16x16x32_bf16(af[i], bf[j], acc[i][j], 0, 0, 0);
  }

#pragma unroll
  for (int i = 0; i < 4; i++) {
    int row0 = (int)bm + wm * 64 + i * 16 + g * 4;
#pragma unroll
    for (int j = 0; j < 4; j++) {
      int col = (int)bn + wn * 64 + j * 16 + li;
      float bvv = bias[col];
#pragma unroll
      for (int jj = 0; jj < 4; jj++)
        out[(long)(row0 + jj) * 1024 + col] = acc[i][j][jj] + bvv;
    }
  }
}

// ---------------- fused scores/softmax/PV (K in LDS, P-in-reg) -------------
__global__ __launch_bounds__(256, 4) void attn_kernel(
    const unsigned short* __restrict__ q,    // (BH,S,64)
    const unsigned short* __restrict__ k,    // (BH,S,64) plain
    const unsigned short* __restrict__ vt,   // (BH,64,S)
    const unsigned int* __restrict__ mpk,    // packed mask
    float* __restrict__ attn,                // (BH,S,S) f32
    unsigned short* __restrict__ ctx) {      // (B,S,D) bf16
  __shared__ unsigned short k_lds[128 * 72];   // [key][dd] pitch 72
  __shared__ unsigned short vt_lds[64 * 136];  // [dd][pi-key] pitch 136
  const int tid = threadIdx.x;
  const int lane = tid & 63, wid = tid >> 6;
  const int g = lane >> 4, li = lane & 15;
  // XCD-cluster swizzle (bijective): heads 8c..8c+7 -> XCD c
  const int p0 = blockIdx.x + 32 * blockIdx.y;
  const int xcd = p0 & 7, q8 = p0 >> 3;
  const int bx = q8 & 31;
  const int bh = xcd * 8 + (q8 >> 5);
  const int b = bh >> 4, h = bh & 15;
  const int qw = bx * 64 + wid * 16;
  const int qs = qw + li;  // per-lane score row

  const unsigned short* qp = q + ((long)bh * S_ + qw) * 64;
  const short8 aq0 = *(const short8*)(qp + li * 64 + g * 8);
  const short8 aq1 = *(const short8*)(qp + li * 64 + 32 + g * 8);
  const unsigned int* mp = mpk + (((long)b * S_ + qs) * 16) * 4 + g;

  const unsigned short* kbase = k + (long)bh * S_ * 64;
  const unsigned short* vbase = vt + (long)bh * 64 * S_;
  // precomputed per-thread offsets
  int kst[4], kgo[4], vst[4], vgo[4];
#pragma unroll
  for (int p = 0; p < 4; p++) {
    int e = (p * 256 + tid) * 8;
    int krr = e >> 6, kcc = e & 63;    // K tile 128x64
    kst[p] = krr * 72 + kcc;
    kgo[p] = krr * 64 + kcc;
    int vrr = e >> 7, vcc = e & 127;   // V tile 64x128
    // pi-permuted store base within 32-key chunk
    int c0 = ((vcc >> 5) << 5) + ((vcc & 8) << 1) + ((vcc & 16) >> 2);
    vst[p] = vrr * 136 + c0;
    vgo[p] = vrr * S_ + vcc;
  }

  // ---- pass 1: denominators ----
  float lsum = 0.f;
  short8 kreg[4];
#pragma unroll
  for (int p = 0; p < 4; p++)
    kreg[p] = *(const short8*)(kbase + kgo[p]);
  unsigned int mb_n = mp[0];
  for (int kt = 0; kt < 16; ++kt) {
    __syncthreads();
#pragma unroll
    for (int p = 0; p < 4; p++)
      *(short8*)(&k_lds[kst[p]]) = kreg[p];
    unsigned int mb = mb_n;
    if (kt < 15) {
#pragma unroll
      for (int p = 0; p < 4; p++)
        kreg[p] = *(const short8*)(kbase + (kt + 1) * 8192 + kgo[p]);
      mb_n = mp[(kt + 1) * 4];
    }
    __syncthreads();
#pragma unroll
    for (int nb = 0; nb < 8; nb++) {
      short8 b0 = *(const short8*)(&k_lds[(nb * 16 + li) * 72 + g * 8]);
      short8 b1 = *(const short8*)(&k_lds[(nb * 16 + li) * 72 + 32 + g * 8]);
      f32x4 s = (f32x4){0.f, 0.f, 0.f, 0.f};
      __builtin_amdgcn_s_setprio(1);
      s = __builtin_amdgcn_mfma_f32_16x16x32_bf16(b0, aq0, s, 0, 0, 0);
      s = __builtin_amdgcn_mfma_f32_16x16x32_bf16(b1, aq1, s, 0, 0, 0);
      __builtin_amdgcn_s_setprio(0);
#pragma unroll
      for (int r = 0; r < 4; r++) {
        float sc = s[r] * 0.125f + (((mb >> (nb * 4 + r)) & 1u) ? 0.f : -1e9f);
        lsum += __expf(sc);
      }
    }
  }
  lsum += __shfl_xor(lsum, 16);
  lsum += __shfl_xor(lsum, 32);
  const float linv = (lsum > 0.f) ? 1.0f / lsum : 0.f;

  // ---- pass 2: probs + PV ----
  f32x4 c[4];
#pragma unroll
  for (int i = 0; i < 4; i++) c[i] = (f32x4){0.f, 0.f, 0.f, 0.f};

  short8 vreg[4];
#pragma unroll
  for (int p = 0; p < 4; p++) {
    kreg[p] = *(const short8*)(kbase + kgo[p]);
    vreg[p] = *(const short8*)(vbase + vgo[p]);
  }
  mb_n = mp[0];
  for (int kt = 0; kt < 16; ++kt) {
    __syncthreads();
#pragma unroll
    for (int p = 0; p < 4; p++) {
      *(short8*)(&k_lds[kst[p]]) = kreg[p];
      // pi-permuted V store: split short8 into two b64 halves
      ushort4* vh = (ushort4*)&vreg[p];
      *(ushort4*)(&vt_lds[vst[p]]) = vh[0];
      *(ushort4*)(&vt_lds[vst[p] + 8]) = vh[1];
    }
    unsigned int mb = mb_n;
    if (kt < 15) {
#pragma unroll
      for (int p = 0; p < 4; p++) {
        kreg[p] = *(const short8*)(kbase + (kt + 1) * 8192 + kgo[p]);
        vreg[p] = *(const short8*)(vbase + (kt + 1) * 128 + vgo[p]);
      }
      mb_n = mp[(kt + 1) * 4];
    }
    __syncthreads();
    float* arow = attn + ((long)bh * S_ + qs) * S_ + kt * 128;
    short8 pu2[4];  // per-lane P fragments, pi-key order
#pragma unroll
    for (int nb = 0; nb < 8; nb++) {
      short8 b0 = *(const short8*)(&k_lds[(nb * 16 + li) * 72 + g * 8]);
      short8 b1 = *(const short8*)(&k_lds[(nb * 16 + li) * 72 + 32 + g * 8]);
      f32x4 s = (f32x4){0.f, 0.f, 0.f, 0.f};
      __builtin_amdgcn_s_setprio(1);
      s = __builtin_amdgcn_mfma_f32_16x16x32_bf16(b0, aq0, s, 0, 0, 0);
      s = __builtin_amdgcn_mfma_f32_16x16x32_bf16(b1, aq1, s, 0, 0, 0);
      __builtin_amdgcn_s_setprio(0);
      f32x4 pf;
      ushort4 pu;
#pragma unroll
      for (int r = 0; r < 4; r++) {
        float sc = s[r] * 0.125f + (((mb >> (nb * 4 + r)) & 1u) ? 0.f : -1e9f);
        float pv = __expf(sc) * linv;
        pf[r] = pv;
        pu[r] = f2b(pv);
      }
      __builtin_nontemporal_store(pf, (f32x4*)(arow + nb * 16 + g * 4));
      ((ushort4*)&pu2[nb >> 1])[nb & 1] = pu;
    }
    __builtin_amdgcn_s_setprio(1);
#pragma unroll
    for (int kc = 0; kc < 4; kc++) {
      short8 ap = pu2[kc];
#pragma unroll
      for (int nb2 = 0; nb2 < 4; nb2++) {
        short8 bv =
            *(const short8*)(&vt_lds[(nb2 * 16 + li) * 136 + kc * 32 + g * 8]);
        c[nb2] = __builtin_amdgcn_mfma_f32_16x16x32_bf16(ap, bv, c[nb2], 0, 0, 0);
      }
    }
    __builtin_amdgcn_s_setprio(0);
  }

#pragma unroll
  for (int nb2 = 0; nb2 < 4; nb2++) {
#pragma unroll
    for (int j = 0; j < 4; j++) {
      int qrow = qw + g * 4 + j;
      ctx[((long)(b * S_ + qrow)) * D_ + h * 64 + nb2 * 16 + li] = f2b(c[nb2][j]);
    }
  }
}

extern "C" void kernel_launch(void* const* d_in, const int* in_sizes, int n_in,
                              void* d_out, int out_size, void* d_ws, size_t ws_size,
                              hipStream_t stream) {
  const float* Q = (const float*)d_in[0];
  const float* K = (const float*)d_in[1];
  const float* V = (const float*)d_in[2];
  const int* mask = (const int*)d_in[3];
  const float* Wq = (const float*)d_in[4];
  const float* bq = (const float*)d_in[5];
  const float* Wk = (const float*)d_in[6];
  const float* bk = (const float*)d_in[7];
  const float* Wv = (const float*)d_in[8];
  const float* bv = (const float*)d_in[9];
  const float* Wo = (const float*)d_in[10];
  const float* bo = (const float*)d_in[11];

  float* out = (float*)d_out;  // (B,S,D) f32
  float* attn = out + TSZ;     // (B,H,S,S) f32
  // packed mask (2 MB) lives in the out region; overwritten by final GEMM
  unsigned int* mpack = (unsigned int*)d_out;

  unsigned short* ws = (unsigned short*)d_ws;
  unsigned short* qh = ws;              // (BH,S,64) bf16
  unsigned short* kh = ws + TSZ;        // (BH,S,64)
  unsigned short* vt = ws + 2 * TSZ;    // (BH,64,S)
  unsigned short* ctx = ws + 3 * TSZ;   // (B,S,D) bf16
  unsigned short* qbf = ws + 4 * TSZ;   // bf16 inputs
  unsigned short* kbf = ws + 5 * TSZ;
  unsigned short* vbf = ws + 6 * TSZ;
  unsigned short* wtq = ws + 7 * TSZ;
  unsigned short* wtk = wtq + 1048576;
  unsigned short* wtv = wtk + 1048576;
  unsigned short* wto = wtv + 1048576;

  dim3 bb(256);
  mask_pack<<<512, bb, 0, stream>>>(mask, mpack);
  cvt3<<<12288, bb, 0, stream>>>(Q, K, V, qbf, kbf, vbf);
  transpose_w4<<<dim3(16, 16, 4), bb, 0, stream>>>(Wq, Wk, Wv, Wo, wtq, wtk,
                                                   wtv, wto);
  qkv_gemm<<<dim3(64, 8, 3), bb, 0, stream>>>(qbf, kbf, vbf, wtq, wtk, wtv, bq,
                                              bk, bv, qh, kh, vt);
  attn_kernel<<<dim3(32, 64), bb, 0, stream>>>(qh, kh, vt, mpack, attn, ctx);
  wo_gemm<<<dim3(64, 8), bb, 0, stream>>>(ctx, wto, bo, out);
}